// Round 3
// baseline (444.430 us; speedup 1.0000x reference)
//
#include <hip/hip_runtime.h>

// SelfAttention B=8 S=2048 D=1024 fp32 -> fp32, bf16 MFMA internally.
// R7: single-barrier double-buffered K-loop (catalog "minimum 2-phase"):
//     STAGE(buf^1, t+1) issued BEFORE frag_mfma(buf), one __syncthreads per
//     K-step (its vmcnt(0) is the counted wait). Next-tile global_load_lds
//     latency hides under ds_read+MFMA; barrier count halves. LDS 32KB/block.
//     proj A-path: 2-deep reg pipeline (regs hold A(t+1) at iter top, cast+
//     ds_write to alt buf, issue A(t+2) loads pre-MFMA).
// Pipeline:
//   build_idx; castW (one launch);
//   proj_gemm_all (one dispatch, z=24): Q->Qp | K gather->Kc | V gather->Vtc^T
//   scores GEMM: p=(gn<cnt)?exp(s/32):0 -> bf16 probs + atomic rowsum
//   PV GEMM (K limited to cntp[b]), epilogue /rowsum -> fp32 out.
// GEMM core: 128x128 tile, BK=32, 4 waves, 16x16x32 bf16 MFMA, dbuf LDS,
// B staging async global_load_lds width=16, native bf16 cvt.
// Workspace (~167MB): Qp[0,32M) Kc[32,64M) Vtc[64,96M) probs[96,160M)
//   weights[160,166M) rowsum/idx/cnt/cntp after.

#define BATCH 8
#define SEQ   2048
#define DM    1024

typedef __bf16 bf16x8 __attribute__((ext_vector_type(8)));
typedef float  f32x4  __attribute__((ext_vector_type(4)));
typedef unsigned short ushort8 __attribute__((ext_vector_type(8)));
typedef unsigned short ushort4v __attribute__((ext_vector_type(4)));

__device__ __forceinline__ unsigned short f2b(float f) {
    __bf16 h = (__bf16)f;               // v_cvt_pk_bf16_f32 pairs (RNE)
    return __builtin_bit_cast(unsigned short, h);
}

__device__ __forceinline__ void stage_async(const unsigned short* g,
                                            unsigned short* l) {
    __builtin_amdgcn_global_load_lds(
        (const __attribute__((address_space(1))) void*)g,
        (__attribute__((address_space(3))) void*)l, 16, 0, 0);
}

// fragment load + 4x4 MFMA for one BK=32 staged tile
__device__ __forceinline__ void frag_mfma(const unsigned short* As,
                                          const unsigned short* Bs,
                                          f32x4 acc[4][4], int waveM, int waveN,
                                          int quad, int l16) {
    bf16x8 af[4], bf[4];
#pragma unroll
    for (int i = 0; i < 4; ++i)
        af[i] = *(const bf16x8*)(As + (waveM * 64 + i * 16 + l16) * 32 + quad * 8);
#pragma unroll
    for (int j = 0; j < 4; ++j)
        bf[j] = *(const bf16x8*)(Bs + (waveN * 64 + j * 16 + l16) * 32 + quad * 8);
#pragma unroll
    for (int i = 0; i < 4; ++i)
#pragma unroll
        for (int j = 0; j < 4; ++j)
            acc[i][j] = __builtin_amdgcn_mfma_f32_16x16x32_bf16(
                af[i], bf[j], acc[i][j], 0, 0, 0);
}

// ---------------- per-batch mask compaction index ----------------
__global__ __launch_bounds__(256) void build_idx(
    const int* __restrict__ mask, int* __restrict__ idx,
    int* __restrict__ cnt, int* __restrict__ cntp) {
    const int b = blockIdx.x;
    const int* m = mask + b * SEQ;
    const int t = threadIdx.x;
    __shared__ int sums[256];
    int loc[8], s = 0;
#pragma unroll
    for (int u = 0; u < 8; ++u) { loc[u] = (m[t * 8 + u] != 0); s += loc[u]; }
    sums[t] = s;
    __syncthreads();
    for (int off = 1; off < 256; off <<= 1) {
        int v = (t >= off) ? sums[t - off] : 0;
        __syncthreads();
        sums[t] += v;
        __syncthreads();
    }
    int base = sums[t] - s;   // exclusive prefix
#pragma unroll
    for (int u = 0; u < 8; ++u)
        if (loc[u]) idx[b * SEQ + base++] = t * 8 + u;
    if (t == 255) {
        cnt[b] = sums[255];
        cntp[b] = (sums[255] + 127) & ~127;
    }
}

// ---------------- cast fp32 -> bf16 (all three weight matrices) ----------------
__global__ void cast_bf16_all(const float* __restrict__ Wq,
                              const float* __restrict__ Wk,
                              const float* __restrict__ Wv,
                              unsigned short* __restrict__ wq,
                              unsigned short* __restrict__ wk,
                              unsigned short* __restrict__ wv) {
    const int p = blockIdx.x >> 9;          // 512 blocks per matrix
    const int lb = blockIdx.x & 511;
    const float* src = (p == 0) ? Wq : (p == 1) ? Wk : Wv;
    unsigned short* dst = (p == 0) ? wq : (p == 1) ? wk : wv;
    int i = lb * blockDim.x + threadIdx.x;  // < 131072
    const f32x4* s4 = (const f32x4*)src;
    f32x4 a = s4[2 * i], b = s4[2 * i + 1];
    ushort8 o;
    o[0] = f2b(a[0]); o[1] = f2b(a[1]); o[2] = f2b(a[2]); o[3] = f2b(a[3]);
    o[4] = f2b(b[0]); o[5] = f2b(b[1]); o[6] = f2b(b[2]); o[7] = f2b(b[3]);
    ((ushort8*)dst)[i] = o;
}

// ------------- projection GEMM body, dbuf single-barrier loop -------------
// C[M,N] = cast(X)[M,K] * W[N,K]^T + bias.  X fp32 (gathered rows if GATHER),
// W bf16 async-staged.  TROUT: write C^T -> C[b][n][m] (V path).
template <bool GATHER, bool TROUT>
__device__ __forceinline__ void proj_body(
    const float* __restrict__ X, const unsigned short* __restrict__ W,
    unsigned short* __restrict__ C, const float* __restrict__ bias,
    const int* __restrict__ idx, const int* __restrict__ cnt,
    const int* __restrict__ cntp, int bz, int i2,
    unsigned short* As0, unsigned short* As1,
    unsigned short* Bs0, unsigned short* Bs1) {
    const int n0 = (i2 & 7) * 128;
    const int m0 = (i2 >> 3) * 128;
    if (GATHER && m0 >= cntp[bz]) return;

    const int tid = threadIdx.x;
    const int wave = tid >> 6, lane = tid & 63;
    const int waveM = wave >> 1, waveN = wave & 1;
    const int quad = lane >> 4, l16 = lane & 15;

    f32x4 acc[4][4] = {};

    // A staging: thread -> (row = tid>>1, 16-col half)
    const int arow = tid >> 1;
    const int col0 = (tid & 1) * 16;
    const float* rp;
    if (GATHER) {
        const int gm = m0 + arow;
        rp = (gm < cnt[bz])
                 ? X + ((size_t)bz * SEQ + idx[bz * SEQ + gm]) * DM + col0
                 : nullptr;
    } else {
        rp = X + ((size_t)bz * SEQ + m0 + arow) * DM + col0;
    }
    const int lAoff = arow * 32 + col0;

    // B (weights) async staging offsets
    const int sr = lane >> 2, sc = (lane & 3) * 8;
    const unsigned short* gB = W + (size_t)(n0 + wave * 32 + sr) * DM + sc;
    const int lBoff = (wave * 32 + sr) * 32 + sc;

    const bool haveA = (!GATHER) || (rp != nullptr);

    // ---- prologue: tile 0 -> buf0; A(1) loads in flight ----
    f32x4 a0 = {}, a1 = {}, a2 = {}, a3 = {};
    if (haveA) {
        const f32x4* p4 = (const f32x4*)rp;
        a0 = p4[0]; a1 = p4[1]; a2 = p4[2]; a3 = p4[3];
    }
    stage_async(gB, Bs0 + lBoff);
    stage_async(gB + 16 * DM, Bs0 + lBoff + 16 * 32);
    {
        ushort8 o0, o1;
        o0[0] = f2b(a0[0]); o0[1] = f2b(a0[1]); o0[2] = f2b(a0[2]); o0[3] = f2b(a0[3]);
        o0[4] = f2b(a1[0]); o0[5] = f2b(a1[1]); o0[6] = f2b(a1[2]); o0[7] = f2b(a1[3]);
        o1[0] = f2b(a2[0]); o1[1] = f2b(a2[1]); o1[2] = f2b(a2[2]); o1[3] = f2b(a2[3]);
        o1[4] = f2b(a3[0]); o1[5] = f2b(a3[1]); o1[6] = f2b(a3[2]); o1[7] = f2b(a3[3]);
        *(ushort8*)(As0 + lAoff) = o0;
        *(ushort8*)(As0 + lAoff + 8) = o1;
    }
    if (haveA) {
        const f32x4* p4 = (const f32x4*)(rp + 32);
        a0 = p4[0]; a1 = p4[1]; a2 = p4[2]; a3 = p4[3];
    }
    __syncthreads();

    int cur = 0;
    for (int kt = 0; kt < DM; kt += 32) {
        const int nx = kt + 32;
        if (nx < DM) {
            unsigned short* Asn = cur ? As0 : As1;
            unsigned short* Bsn = cur ? Bs0 : Bs1;
            // B stage for next tile (flies during MFMA below)
            stage_async(gB + nx, Bsn + lBoff);
            stage_async(gB + nx + 16 * DM, Bsn + lBoff + 16 * 32);
            // cast A(nx) (regs ready: drained at previous barrier)
            ushort8 o0, o1;
            o0[0] = f2b(a0[0]); o0[1] = f2b(a0[1]); o0[2] = f2b(a0[2]); o0[3] = f2b(a0[3]);
            o0[4] = f2b(a1[0]); o0[5] = f2b(a1[1]); o0[6] = f2b(a1[2]); o0[7] = f2b(a1[3]);
            o1[0] = f2b(a2[0]); o1[1] = f2b(a2[1]); o1[2] = f2b(a2[2]); o1[3] = f2b(a2[3]);
            o1[4] = f2b(a3[0]); o1[5] = f2b(a3[1]); o1[6] = f2b(a3[2]); o1[7] = f2b(a3[3]);
            *(ushort8*)(Asn + lAoff) = o0;
            *(ushort8*)(Asn + lAoff + 8) = o1;
            // issue A(nx+32) loads; they drain at this iter's barrier
            if (haveA && nx + 32 < DM) {
                const f32x4* p4 = (const f32x4*)(rp + nx + 32);
                a0 = p4[0]; a1 = p4[1]; a2 = p4[2]; a3 = p4[3];
            }
        }
        frag_mfma(cur ? As1 : As0, cur ? Bs1 : Bs0, acc, waveM, waveN, quad, l16);
        __syncthreads();
        cur ^= 1;
    }

    if (!TROUT) {
        unsigned short* Cb = C + (size_t)bz * SEQ * DM;
#pragma unroll
        for (int i = 0; i < 4; ++i) {
            const int gmb = m0 + waveM * 64 + i * 16 + quad * 4;
#pragma unroll
            for (int j = 0; j < 4; ++j) {
                const int gn = n0 + waveN * 64 + j * 16 + l16;
                const float bv = bias[gn];
#pragma unroll
                for (int r = 0; r < 4; ++r)
                    Cb[(size_t)(gmb + r) * DM + gn] = f2b(acc[i][j][r] + bv);
            }
        }
    } else {
        unsigned short* Cb = C + (size_t)bz * (size_t)DM * SEQ;
#pragma unroll
        for (int i = 0; i < 4; ++i) {
            const int gmb = m0 + waveM * 64 + i * 16 + quad * 4;  // compacted j
#pragma unroll
            for (int j = 0; j < 4; ++j) {
                const int gn = n0 + waveN * 64 + j * 16 + l16;
                const float bv = bias[gn];
                ushort4v o;
#pragma unroll
                for (int r = 0; r < 4; ++r) o[r] = f2b(acc[i][j][r] + bv);
                *(ushort4v*)(Cb + (size_t)gn * SEQ + gmb) = o;
            }
        }
    }
}

// Merged Q/K/V projection dispatch.  grid (8,16,24): linear l in [0,3072);
// p = l>>10 selects projection; batch = l&7 keeps batch<->XCD affinity.
__global__ __launch_bounds__(256) void proj_gemm_all(
    const float* __restrict__ q, const float* __restrict__ k,
    const float* __restrict__ v, const unsigned short* __restrict__ wq,
    const unsigned short* __restrict__ wk, const unsigned short* __restrict__ wv,
    unsigned short* __restrict__ Qp, unsigned short* __restrict__ Kc,
    unsigned short* __restrict__ Vt, const float* __restrict__ bq,
    const float* __restrict__ bk, const float* __restrict__ bv,
    const int* __restrict__ idx, const int* __restrict__ cnt,
    const int* __restrict__ cntp) {
    const int l = blockIdx.x + 8 * (blockIdx.y + 16 * blockIdx.z);
    const int p = l >> 10;
    const int bz = l & 7;
    const int i2 = (l & 1023) >> 3;   // 0..127

    __shared__ __align__(16) unsigned short As[2][128 * 32];
    __shared__ __align__(16) unsigned short Bs[2][128 * 32];

    if (p == 0)
        proj_body<false, false>(q, wq, Qp, bq, nullptr, nullptr, nullptr, bz, i2,
                                As[0], As[1], Bs[0], Bs[1]);
    else if (p == 1)
        proj_body<true, false>(k, wk, Kc, bk, idx, cnt, cntp, bz, i2,
                               As[0], As[1], Bs[0], Bs[1]);
    else
        proj_body<true, true>(v, wv, Vt, bv, idx, cnt, cntp, bz, i2,
                              As[0], As[1], Bs[0], Bs[1]);
}

// ---------------- scores GEMM: probs = exp(Q.Kc^T/32), + rowsum ----------------
// grid (16,16,8); swizzle batch = linear&7 (one batch per XCD: Qp_b+Kc_b in L2).
__global__ __launch_bounds__(256) void scores_gemm(
    const unsigned short* __restrict__ Qp, const unsigned short* __restrict__ Kc,
    unsigned short* __restrict__ P, float* __restrict__ rowsum,
    const int* __restrict__ cnt, const int* __restrict__ cntp, float scale) {
    const int l = blockIdx.x + 16 * (blockIdx.y + 16 * blockIdx.z);
    const int bz = l & 7;
    const int i2 = l >> 3;            // 0..255
    const int n0 = (i2 & 15) * 128;
    const int m0 = (i2 >> 4) * 128;
    if (n0 >= cntp[bz]) return;

    const int tid = threadIdx.x;
    const int wave = tid >> 6, lane = tid & 63;
    const int waveM = wave >> 1, waveN = wave & 1;
    const int quad = lane >> 4, l16 = lane & 15;

    __shared__ __align__(16) unsigned short As[2][128 * 32];
    __shared__ __align__(16) unsigned short Bs[2][128 * 32];
    f32x4 acc[4][4] = {};

    const unsigned short* Ag = Qp + (size_t)bz * SEQ * DM;
    const unsigned short* Bg = Kc + (size_t)bz * SEQ * DM;
    const int sr = lane >> 2, sc = (lane & 3) * 8;
    const unsigned short* gA = Ag + (size_t)(m0 + wave * 32 + sr) * DM + sc;
    const unsigned short* gB = Bg + (size_t)(n0 + wave * 32 + sr) * DM + sc;
    const int loff = (wave * 32 + sr) * 32 + sc;

    stage_async(gA, As[0] + loff);
    stage_async(gA + 16 * DM, As[0] + loff + 16 * 32);
    stage_async(gB, Bs[0] + loff);
    stage_async(gB + 16 * DM, Bs[0] + loff + 16 * 32);
    __syncthreads();

    int cur = 0;
    for (int kt = 0; kt < DM; kt += 32) {
        const int nx = kt + 32;
        if (nx < DM) {
            unsigned short* Asn = cur ? As[0] : As[1];
            unsigned short* Bsn = cur ? Bs[0] : Bs[1];
            stage_async(gA + nx, Asn + loff);
            stage_async(gA + nx + 16 * DM, Asn + loff + 16 * 32);
            stage_async(gB + nx, Bsn + loff);
            stage_async(gB + nx + 16 * DM, Bsn + loff + 16 * 32);
        }
        frag_mfma(cur ? As[1] : As[0], cur ? Bs[1] : Bs[0], acc,
                  waveM, waveN, quad, l16);
        __syncthreads();
        cur ^= 1;
    }

    unsigned short* Cb = P + (size_t)bz * SEQ * SEQ;
    const int cn = cnt[bz];
#pragma unroll
    for (int i = 0; i < 4; ++i) {
        const int gmb = m0 + waveM * 64 + i * 16 + quad * 4;
        float rpart[4] = {0.f, 0.f, 0.f, 0.f};
#pragma unroll
        for (int j = 0; j < 4; ++j) {
            const int gn = n0 + waveN * 64 + j * 16 + l16;
            const float mv = (gn < cn) ? 1.0f : 0.0f;
#pragma unroll
            for (int r = 0; r < 4; ++r) {
                const float p = mv * __expf(acc[i][j][r] * scale);
                rpart[r] += p;
                Cb[(size_t)(gmb + r) * SEQ + gn] = f2b(p);
            }
        }
#pragma unroll
        for (int r = 0; r < 4; ++r) {
            float s = rpart[r];
            s += __shfl_xor(s, 1, 64);
            s += __shfl_xor(s, 2, 64);
            s += __shfl_xor(s, 4, 64);
            s += __shfl_xor(s, 8, 64);
            if (l16 == 0)
                atomicAdd(&rowsum[bz * SEQ + gmb + r], s);
        }
    }
}

// ---------------- PV GEMM: out = (P.Vtc^T) / rowsum ----------------
// grid (8,16,8); swizzle batch = linear&7.
__global__ __launch_bounds__(256) void pv_gemm(
    const unsigned short* __restrict__ P, const unsigned short* __restrict__ Vt,
    float* __restrict__ O, const float* __restrict__ rowsum,
    const int* __restrict__ cntp) {
    const int l = blockIdx.x + 8 * (blockIdx.y + 16 * blockIdx.z);
    const int bz = l & 7;
    const int i2 = l >> 3;            // 0..127
    const int n0 = (i2 & 7) * 128;
    const int m0 = (i2 >> 3) * 128;
    const int kend = cntp[bz];

    const int tid = threadIdx.x;
    const int wave = tid >> 6, lane = tid & 63;
    const int waveM = wave >> 1, waveN = wave & 1;
    const int quad = lane >> 4, l16 = lane & 15;

    __shared__ __align__(16) unsigned short As[2][128 * 32];
    __shared__ __align__(16) unsigned short Bs[2][128 * 32];
    f32x4 acc[4][4] = {};

    const unsigned short* Ag = P + (size_t)bz * SEQ * SEQ;
    const unsigned short* Bg = Vt + (size_t)bz * (size_t)DM * SEQ;
    const int sr = lane >> 2, sc = (lane & 3) * 8;
    const unsigned short* gA = Ag + (size_t)(m0 + wave * 32 + sr) * SEQ + sc;
    const unsigned short* gB = Bg + (size_t)(n0 + wave * 32 + sr) * SEQ + sc;
    const int loff = (wave * 32 + sr) * 32 + sc;

    stage_async(gA, As[0] + loff);
    stage_async(gA + 16 * SEQ, As[0] + loff + 16 * 32);
    stage_async(gB, Bs[0] + loff);
    stage_async(gB + 16 * SEQ, Bs[0] + loff + 16 * 32);
    __syncthreads();

    int cur = 0;
    for (int kt = 0; kt < kend; kt += 32) {
        const int nx = kt + 32;
        if (nx < kend) {
            unsigned short* Asn = cur ? As[0] : As[1];
            unsigned short* Bsn = cur ? Bs[0] : Bs[1];
            stage_async(gA + nx, Asn + loff);
            stage_async(gA + nx + 16 * SEQ, Asn + loff + 16 * 32);
            stage_async(gB + nx, Bsn + loff);
            stage_async(gB + nx + 16 * SEQ, Bsn + loff + 16 * 32);
        }
        frag_mfma(cur ? As[1] : As[0], cur ? Bs[1] : Bs[0], acc,
                  waveM, waveN, quad, l16);
        __syncthreads();
        cur ^= 1;
    }

    float* Cb = O + (size_t)bz * SEQ * DM;
#pragma unroll
    for (int i = 0; i < 4; ++i) {
        const int gmb = m0 + waveM * 64 + i * 16 + quad * 4;
        float inv[4];
#pragma unroll
        for (int r = 0; r < 4; ++r)
            inv[r] = 1.0f / rowsum[bz * SEQ + gmb + r];
#pragma unroll
        for (int j = 0; j < 4; ++j) {
            const int gn = n0 + waveN * 64 + j * 16 + l16;
#pragma unroll
            for (int r = 0; r < 4; ++r)
                Cb[(size_t)(gmb + r) * DM + gn] = acc[i][j][r] * inv[r];
        }
    }
}

extern "C" void kernel_launch(void* const* d_in, const int* in_sizes, int n_in,
                              void* d_out, int out_size, void* d_ws, size_t ws_size,
                              hipStream_t stream) {
    const float* query = (const float*)d_in[0];
    const float* key_  = (const float*)d_in[1];
    const float* value = (const float*)d_in[2];
    const int*   mask  = (const int*)d_in[3];
    const float* Wq = (const float*)d_in[4];
    const float* bq = (const float*)d_in[5];
    const float* Wk = (const float*)d_in[6];
    const float* bk = (const float*)d_in[7];
    const float* Wv = (const float*)d_in[8];
    const float* bv = (const float*)d_in[9];
    float* out = (float*)d_out;

    char* ws = (char*)d_ws;
    const size_t MB = 1024 * 1024;
    unsigned short* Qp    = (unsigned short*)(ws);             // 32MB
    unsigned short* Kc    = (unsigned short*)(ws + 32 * MB);   // 32MB
    unsigned short* Vtc   = (unsigned short*)(ws + 64 * MB);   // 32MB
    unsigned short* probs = (unsigned short*)(ws + 96 * MB);   // 64MB
    unsigned short* wq    = (unsigned short*)(ws + 160 * MB);  // 2MB
    unsigned short* wk    = (unsigned short*)(ws + 162 * MB);  // 2MB
    unsigned short* wv    = (unsigned short*)(ws + 164 * MB);  // 2MB
    float* rowsum = (float*)(ws + 166 * MB);                   // 64KB
    int*   idx    = (int*)(ws + 166 * MB + 64 * 1024);         // 64KB
    int*   cnt    = (int*)(ws + 166 * MB + 128 * 1024);        // 32B
    int*   cntp   = (int*)(ws + 166 * MB + 128 * 1024 + 64);   // 32B

    hipMemsetAsync(rowsum, 0, (size_t)BATCH * SEQ * sizeof(float), stream);
    build_idx<<<BATCH, 256, 0, stream>>>(mask, idx, cnt, cntp);

    cast_bf16_all<<<1536, 256, 0, stream>>>(Wq, Wk, Wv, wq, wk, wv);

    proj_gemm_all<<<dim3(8, 16, 24), dim3(256), 0, stream>>>(
        query, key_, value, wq, wk, wv, Qp, Kc, Vtc, bq, bk, bv,
        idx, cnt, cntp);

    scores_gemm<<<dim3(16, 16, 8), dim3(256), 0, stream>>>(
        Qp, Kc, probs, rowsum, cnt, cntp, 0.03125f);

    pv_gemm<<<dim3(8, 16, 8), dim3(256), 0, stream>>>(
        probs, Vtc, out, rowsum, cntp);
}

// Round 4
// 435.665 us; speedup vs baseline: 1.0201x; 1.0201x over previous
//
#include <hip/hip_runtime.h>

// SelfAttention B=8 S=2048 D=1024 fp32 -> fp32, bf16 MFMA internally.
// R8: fatter wave tiles to cut LDS-unit throughput (the measured limiter:
//     MFMA 17%/VALU 13%/HBM 13% all idle, LDS-unit audit ~70-100% busy).
//     Wave tile 64x64 -> 64x128 (af[4] x bf[8] -> 32 MFMA): LDS frag reads
//     per FLOP x0.75, A-cast ds_write + barriers per FLOP x0.5.
//     Block tile 128x256 (4 waves 2Mx2N), BK=32, dbuf single-barrier loop.
// Pipeline:
//   build_idx; castW (one launch);
//   proj_gemm_all (one dispatch): Q->Qp | K gather->Kc | V gather->Vtc^T
//   scores GEMM: p=(gn<cnt)?exp(s/32):0 -> bf16 probs + atomic rowsum
//   PV GEMM (K limited to cntp[b]), epilogue /rowsum -> fp32 out.
// Workspace (~167MB): Qp[0,32M) Kc[32,64M) Vtc[64,96M) probs[96,160M)
//   weights[160,166M) rowsum/idx/cnt/cntp after.

#define BATCH 8
#define SEQ   2048
#define DM    1024

typedef __bf16 bf16x8 __attribute__((ext_vector_type(8)));
typedef float  f32x4  __attribute__((ext_vector_type(4)));
typedef unsigned short ushort8 __attribute__((ext_vector_type(8)));
typedef unsigned short ushort4v __attribute__((ext_vector_type(4)));

__device__ __forceinline__ unsigned short f2b(float f) {
    __bf16 h = (__bf16)f;               // v_cvt_pk_bf16_f32 pairs (RNE)
    return __builtin_bit_cast(unsigned short, h);
}

__device__ __forceinline__ void stage_async(const unsigned short* g,
                                            unsigned short* l) {
    __builtin_amdgcn_global_load_lds(
        (const __attribute__((address_space(1))) void*)g,
        (__attribute__((address_space(3))) void*)l, 16, 0, 0);
}

// fragment load + 4x8 MFMA for one BK=32 staged tile.
// As: 128 rows x 32; Bs: 256 rows x 32. Wave tile 64x128.
__device__ __forceinline__ void frag_mfma48(const unsigned short* As,
                                            const unsigned short* Bs,
                                            f32x4 acc[4][8], int waveM,
                                            int waveN, int quad, int l16) {
    bf16x8 af[4], bf[8];
#pragma unroll
    for (int i = 0; i < 4; ++i)
        af[i] = *(const bf16x8*)(As + (waveM * 64 + i * 16 + l16) * 32 + quad * 8);
#pragma unroll
    for (int j = 0; j < 8; ++j)
        bf[j] = *(const bf16x8*)(Bs + (waveN * 128 + j * 16 + l16) * 32 + quad * 8);
#pragma unroll
    for (int i = 0; i < 4; ++i)
#pragma unroll
        for (int j = 0; j < 8; ++j)
            acc[i][j] = __builtin_amdgcn_mfma_f32_16x16x32_bf16(
                af[i], bf[j], acc[i][j], 0, 0, 0);
}

// ---------------- per-batch mask compaction index ----------------
__global__ __launch_bounds__(256) void build_idx(
    const int* __restrict__ mask, int* __restrict__ idx,
    int* __restrict__ cnt, int* __restrict__ cntp) {
    const int b = blockIdx.x;
    const int* m = mask + b * SEQ;
    const int t = threadIdx.x;
    __shared__ int sums[256];
    int loc[8], s = 0;
#pragma unroll
    for (int u = 0; u < 8; ++u) { loc[u] = (m[t * 8 + u] != 0); s += loc[u]; }
    sums[t] = s;
    __syncthreads();
    for (int off = 1; off < 256; off <<= 1) {
        int v = (t >= off) ? sums[t - off] : 0;
        __syncthreads();
        sums[t] += v;
        __syncthreads();
    }
    int base = sums[t] - s;   // exclusive prefix
#pragma unroll
    for (int u = 0; u < 8; ++u)
        if (loc[u]) idx[b * SEQ + base++] = t * 8 + u;
    if (t == 255) {
        cnt[b] = sums[255];
        cntp[b] = (sums[255] + 127) & ~127;
    }
}

// ---------------- cast fp32 -> bf16 (all three weight matrices) ----------------
__global__ void cast_bf16_all(const float* __restrict__ Wq,
                              const float* __restrict__ Wk,
                              const float* __restrict__ Wv,
                              unsigned short* __restrict__ wq,
                              unsigned short* __restrict__ wk,
                              unsigned short* __restrict__ wv) {
    const int p = blockIdx.x >> 9;          // 512 blocks per matrix
    const int lb = blockIdx.x & 511;
    const float* src = (p == 0) ? Wq : (p == 1) ? Wk : Wv;
    unsigned short* dst = (p == 0) ? wq : (p == 1) ? wk : wv;
    int i = lb * blockDim.x + threadIdx.x;  // < 131072
    const f32x4* s4 = (const f32x4*)src;
    f32x4 a = s4[2 * i], b = s4[2 * i + 1];
    ushort8 o;
    o[0] = f2b(a[0]); o[1] = f2b(a[1]); o[2] = f2b(a[2]); o[3] = f2b(a[3]);
    o[4] = f2b(b[0]); o[5] = f2b(b[1]); o[6] = f2b(b[2]); o[7] = f2b(b[3]);
    ((ushort8*)dst)[i] = o;
}

// ------------- projection GEMM body, 128x256 tile, dbuf loop -------------
// C[M,N] = cast(X)[M,K] * W[N,K]^T + bias.  X fp32 (gathered rows if GATHER),
// W bf16 async-staged (256 N-rows).  TROUT: write C^T -> C[b][n][m].
template <bool GATHER, bool TROUT>
__device__ __forceinline__ void proj_body(
    const float* __restrict__ X, const unsigned short* __restrict__ W,
    unsigned short* __restrict__ C, const float* __restrict__ bias,
    const int* __restrict__ idx, const int* __restrict__ cnt,
    const int* __restrict__ cntp, int bz, int mt, int nt,
    unsigned short* As0, unsigned short* As1,
    unsigned short* Bs0, unsigned short* Bs1) {
    const int n0 = nt * 256;
    const int m0 = mt * 128;
    if (GATHER && m0 >= cntp[bz]) return;

    const int tid = threadIdx.x;
    const int wave = tid >> 6, lane = tid & 63;
    const int waveM = wave >> 1, waveN = wave & 1;
    const int quad = lane >> 4, l16 = lane & 15;

    f32x4 acc[4][8] = {};

    // A staging (128 rows): thread -> (row = tid>>1, 16-col half)
    const int arow = tid >> 1;
    const int col0 = (tid & 1) * 16;
    const float* rp;
    if (GATHER) {
        const int gm = m0 + arow;
        rp = (gm < cnt[bz])
                 ? X + ((size_t)bz * SEQ + idx[bz * SEQ + gm]) * DM + col0
                 : nullptr;
    } else {
        rp = X + ((size_t)bz * SEQ + m0 + arow) * DM + col0;
    }
    const int lAoff = arow * 32 + col0;

    // B (weights, 256 rows) async staging: 4 chunks of 64 rows
    const int sr = lane >> 2, sc = (lane & 3) * 8;
    const unsigned short* gB = W + (size_t)(n0 + wave * 16 + sr) * DM + sc;
    const int lBoff = (wave * 16 + sr) * 32 + sc;

    const bool haveA = (!GATHER) || (rp != nullptr);

    // ---- prologue: tile 0 -> buf0; A(1) in regs ----
    f32x4 a0 = {}, a1 = {}, a2 = {}, a3 = {};
    if (haveA) {
        const f32x4* p4 = (const f32x4*)rp;
        a0 = p4[0]; a1 = p4[1]; a2 = p4[2]; a3 = p4[3];
    }
#pragma unroll
    for (int c = 0; c < 4; ++c)
        stage_async(gB + (size_t)c * 64 * DM, Bs0 + lBoff + c * 64 * 32);
    {
        ushort8 o0, o1;
        o0[0] = f2b(a0[0]); o0[1] = f2b(a0[1]); o0[2] = f2b(a0[2]); o0[3] = f2b(a0[3]);
        o0[4] = f2b(a1[0]); o0[5] = f2b(a1[1]); o0[6] = f2b(a1[2]); o0[7] = f2b(a1[3]);
        o1[0] = f2b(a2[0]); o1[1] = f2b(a2[1]); o1[2] = f2b(a2[2]); o1[3] = f2b(a2[3]);
        o1[4] = f2b(a3[0]); o1[5] = f2b(a3[1]); o1[6] = f2b(a3[2]); o1[7] = f2b(a3[3]);
        *(ushort8*)(As0 + lAoff) = o0;
        *(ushort8*)(As0 + lAoff + 8) = o1;
    }
    if (haveA) {
        const f32x4* p4 = (const f32x4*)(rp + 32);
        a0 = p4[0]; a1 = p4[1]; a2 = p4[2]; a3 = p4[3];
    }
    __syncthreads();

    int cur = 0;
    for (int kt = 0; kt < DM; kt += 32) {
        const int nx = kt + 32;
        if (nx < DM) {
            unsigned short* Asn = cur ? As0 : As1;
            unsigned short* Bsn = cur ? Bs0 : Bs1;
#pragma unroll
            for (int c = 0; c < 4; ++c)
                stage_async(gB + (size_t)c * 64 * DM + nx,
                            Bsn + lBoff + c * 64 * 32);
            ushort8 o0, o1;
            o0[0] = f2b(a0[0]); o0[1] = f2b(a0[1]); o0[2] = f2b(a0[2]); o0[3] = f2b(a0[3]);
            o0[4] = f2b(a1[0]); o0[5] = f2b(a1[1]); o0[6] = f2b(a1[2]); o0[7] = f2b(a1[3]);
            o1[0] = f2b(a2[0]); o1[1] = f2b(a2[1]); o1[2] = f2b(a2[2]); o1[3] = f2b(a2[3]);
            o1[4] = f2b(a3[0]); o1[5] = f2b(a3[1]); o1[6] = f2b(a3[2]); o1[7] = f2b(a3[3]);
            *(ushort8*)(Asn + lAoff) = o0;
            *(ushort8*)(Asn + lAoff + 8) = o1;
            if (haveA && nx + 32 < DM) {
                const f32x4* p4 = (const f32x4*)(rp + nx + 32);
                a0 = p4[0]; a1 = p4[1]; a2 = p4[2]; a3 = p4[3];
            }
        }
        frag_mfma48(cur ? As1 : As0, cur ? Bs1 : Bs0, acc, waveM, waveN, quad, l16);
        __syncthreads();
        cur ^= 1;
    }

    if (!TROUT) {
        unsigned short* Cb = C + (size_t)bz * SEQ * DM;
#pragma unroll
        for (int i = 0; i < 4; ++i) {
            const int gmb = m0 + waveM * 64 + i * 16 + quad * 4;
#pragma unroll
            for (int j = 0; j < 8; ++j) {
                const int gn = n0 + waveN * 128 + j * 16 + l16;
                const float bv = bias[gn];
#pragma unroll
                for (int r = 0; r < 4; ++r)
                    Cb[(size_t)(gmb + r) * DM + gn] = f2b(acc[i][j][r] + bv);
            }
        }
    } else {
        unsigned short* Cb = C + (size_t)bz * (size_t)DM * SEQ;
#pragma unroll
        for (int i = 0; i < 4; ++i) {
            const int gmb = m0 + waveM * 64 + i * 16 + quad * 4;  // compacted j
#pragma unroll
            for (int j = 0; j < 8; ++j) {
                const int gn = n0 + waveN * 128 + j * 16 + l16;
                const float bv = bias[gn];
                ushort4v o;
#pragma unroll
                for (int r = 0; r < 4; ++r) o[r] = f2b(acc[i][j][r] + bv);
                *(ushort4v*)(Cb + (size_t)gn * SEQ + gmb) = o;
            }
        }
    }
}

// Merged Q/K/V projection dispatch.  grid (8,16,12): l in [0,1536);
// p = l>>9 selects projection; batch = l&7; tile = (l&511)>>3 (mt 16 x nt 4).
__global__ __launch_bounds__(256, 2) void proj_gemm_all(
    const float* __restrict__ q, const float* __restrict__ k,
    const float* __restrict__ v, const unsigned short* __restrict__ wq,
    const unsigned short* __restrict__ wk, const unsigned short* __restrict__ wv,
    unsigned short* __restrict__ Qp, unsigned short* __restrict__ Kc,
    unsigned short* __restrict__ Vt, const float* __restrict__ bq,
    const float* __restrict__ bk, const float* __restrict__ bv,
    const int* __restrict__ idx, const int* __restrict__ cnt,
    const int* __restrict__ cntp) {
    const int l = blockIdx.x + 8 * (blockIdx.y + 16 * blockIdx.z);
    const int p = l >> 9;
    const int bz = l & 7;
    const int t = (l & 511) >> 3;     // 0..63
    const int nt = t & 3, mt = t >> 2;

    __shared__ __align__(16) unsigned short As[2][128 * 32];
    __shared__ __align__(16) unsigned short Bs[2][256 * 32];

    if (p == 0)
        proj_body<false, false>(q, wq, Qp, bq, nullptr, nullptr, nullptr,
                                bz, mt, nt, As[0], As[1], Bs[0], Bs[1]);
    else if (p == 1)
        proj_body<true, false>(k, wk, Kc, bk, idx, cnt, cntp,
                               bz, mt, nt, As[0], As[1], Bs[0], Bs[1]);
    else
        proj_body<true, true>(v, wv, Vt, bv, idx, cnt, cntp,
                              bz, mt, nt, As[0], As[1], Bs[0], Bs[1]);
}

// ---------------- scores GEMM: probs = exp(Q.Kc^T/32), + rowsum ----------------
// 128x256 tiles: grid (8,16,8): l in [0,1024); bz=l&7; i2=l>>3: nt=i2&7, mt=i2>>3.
__global__ __launch_bounds__(256, 2) void scores_gemm(
    const unsigned short* __restrict__ Qp, const unsigned short* __restrict__ Kc,
    unsigned short* __restrict__ P, float* __restrict__ rowsum,
    const int* __restrict__ cnt, const int* __restrict__ cntp, float scale) {
    const int l = blockIdx.x + 8 * (blockIdx.y + 16 * blockIdx.z);
    const int bz = l & 7;
    const int i2 = l >> 3;            // 0..127
    const int n0 = (i2 & 7) * 256;
    const int m0 = (i2 >> 3) * 128;
    if (n0 >= cntp[bz]) return;

    const int tid = threadIdx.x;
    const int wave = tid >> 6, lane = tid & 63;
    const int waveM = wave >> 1, waveN = wave & 1;
    const int quad = lane >> 4, l16 = lane & 15;

    __shared__ __align__(16) unsigned short As[2][128 * 32];
    __shared__ __align__(16) unsigned short Bs[2][256 * 32];
    f32x4 acc[4][8] = {};

    const unsigned short* Ag = Qp + (size_t)bz * SEQ * DM;
    const unsigned short* Bg = Kc + (size_t)bz * SEQ * DM;
    const int sr = lane >> 2, sc = (lane & 3) * 8;
    const unsigned short* gA = Ag + (size_t)(m0 + wave * 32 + sr) * DM + sc;
    const unsigned short* gB = Bg + (size_t)(n0 + wave * 16 + sr) * DM + sc;
    const int lAoff = (wave * 32 + sr) * 32 + sc;
    const int lBoff = (wave * 16 + sr) * 32 + sc;

    stage_async(gA, As[0] + lAoff);
    stage_async(gA + 16 * DM, As[0] + lAoff + 16 * 32);
#pragma unroll
    for (int c = 0; c < 4; ++c)
        stage_async(gB + (size_t)c * 64 * DM, Bs[0] + lBoff + c * 64 * 32);
    __syncthreads();

    int cur = 0;
    for (int kt = 0; kt < DM; kt += 32) {
        const int nx = kt + 32;
        if (nx < DM) {
            unsigned short* Asn = cur ? As[0] : As[1];
            unsigned short* Bsn = cur ? Bs[0] : Bs[1];
            stage_async(gA + nx, Asn + lAoff);
            stage_async(gA + nx + 16 * DM, Asn + lAoff + 16 * 32);
#pragma unroll
            for (int c = 0; c < 4; ++c)
                stage_async(gB + (size_t)c * 64 * DM + nx,
                            Bsn + lBoff + c * 64 * 32);
        }
        frag_mfma48(cur ? As[1] : As[0], cur ? Bs[1] : Bs[0], acc,
                    waveM, waveN, quad, l16);
        __syncthreads();
        cur ^= 1;
    }

    unsigned short* Cb = P + (size_t)bz * SEQ * SEQ;
    const int cn = cnt[bz];
#pragma unroll
    for (int i = 0; i < 4; ++i) {
        const int gmb = m0 + waveM * 64 + i * 16 + quad * 4;
        float rpart[4] = {0.f, 0.f, 0.f, 0.f};
#pragma unroll
        for (int j = 0; j < 8; ++j) {
            const int gn = n0 + waveN * 128 + j * 16 + l16;
            const float mv = (gn < cn) ? 1.0f : 0.0f;
#pragma unroll
            for (int r = 0; r < 4; ++r) {
                const float p = mv * __expf(acc[i][j][r] * scale);
                rpart[r] += p;
                Cb[(size_t)(gmb + r) * SEQ + gn] = f2b(p);
            }
        }
#pragma unroll
        for (int r = 0; r < 4; ++r) {
            float s = rpart[r];
            s += __shfl_xor(s, 1, 64);
            s += __shfl_xor(s, 2, 64);
            s += __shfl_xor(s, 4, 64);
            s += __shfl_xor(s, 8, 64);
            if (l16 == 0)
                atomicAdd(&rowsum[bz * SEQ + gmb + r], s);
        }
    }
}

// ---------------- PV GEMM: out = (P.Vtc^T) / rowsum ----------------
// 128x256 tiles: grid (8,8,8): l in [0,512); bz=l&7; i2=l>>3: nt=i2&3, mt=i2>>2.
__global__ __launch_bounds__(256, 2) void pv_gemm(
    const unsigned short* __restrict__ P, const unsigned short* __restrict__ Vt,
    float* __restrict__ O, const float* __restrict__ rowsum,
    const int* __restrict__ cntp) {
    const int l = blockIdx.x + 8 * (blockIdx.y + 8 * blockIdx.z);
    const int bz = l & 7;
    const int i2 = l >> 3;            // 0..63
    const int n0 = (i2 & 3) * 256;
    const int m0 = (i2 >> 2) * 128;
    const int kend = cntp[bz];

    const int tid = threadIdx.x;
    const int wave = tid >> 6, lane = tid & 63;
    const int waveM = wave >> 1, waveN = wave & 1;
    const int quad = lane >> 4, l16 = lane & 15;

    __shared__ __align__(16) unsigned short As[2][128 * 32];
    __shared__ __align__(16) unsigned short Bs[2][256 * 32];
    f32x4 acc[4][8] = {};

    const unsigned short* Ag = P + (size_t)bz * SEQ * SEQ;
    const unsigned short* Bg = Vt + (size_t)bz * (size_t)DM * SEQ;
    const int sr = lane >> 2, sc = (lane & 3) * 8;
    const unsigned short* gA = Ag + (size_t)(m0 + wave * 32 + sr) * SEQ + sc;
    const unsigned short* gB = Bg + (size_t)(n0 + wave * 16 + sr) * SEQ + sc;
    const int lAoff = (wave * 32 + sr) * 32 + sc;
    const int lBoff = (wave * 16 + sr) * 32 + sc;

    stage_async(gA, As[0] + lAoff);
    stage_async(gA + 16 * SEQ, As[0] + lAoff + 16 * 32);
#pragma unroll
    for (int c = 0; c < 4; ++c)
        stage_async(gB + (size_t)c * 64 * SEQ, Bs[0] + lBoff + c * 64 * 32);
    __syncthreads();

    int cur = 0;
    for (int kt = 0; kt < kend; kt += 32) {
        const int nx = kt + 32;
        if (nx < kend) {
            unsigned short* Asn = cur ? As[0] : As[1];
            unsigned short* Bsn = cur ? Bs[0] : Bs[1];
            stage_async(gA + nx, Asn + lAoff);
            stage_async(gA + nx + 16 * SEQ, Asn + lAoff + 16 * 32);
#pragma unroll
            for (int c = 0; c < 4; ++c)
                stage_async(gB + (size_t)c * 64 * SEQ + nx,
                            Bsn + lBoff + c * 64 * 32);
        }
        frag_mfma48(cur ? As[1] : As[0], cur ? Bs[1] : Bs[0], acc,
                    waveM, waveN, quad, l16);
        __syncthreads();
        cur ^= 1;
    }

    float* Cb = O + (size_t)bz * SEQ * DM;
#pragma unroll
    for (int i = 0; i < 4; ++i) {
        const int gmb = m0 + waveM * 64 + i * 16 + quad * 4;
        float inv[4];
#pragma unroll
        for (int r = 0; r < 4; ++r)
            inv[r] = 1.0f / rowsum[bz * SEQ + gmb + r];
#pragma unroll
        for (int j = 0; j < 8; ++j) {
            const int gn = n0 + waveN * 128 + j * 16 + l16;
#pragma unroll
            for (int r = 0; r < 4; ++r)
                Cb[(size_t)(gmb + r) * DM + gn] = acc[i][j][r] * inv[r];
        }
    }
}

extern "C" void kernel_launch(void* const* d_in, const int* in_sizes, int n_in,
                              void* d_out, int out_size, void* d_ws, size_t ws_size,
                              hipStream_t stream) {
    const float* query = (const float*)d_in[0];
    const float* key_  = (const float*)d_in[1];
    const float* value = (const float*)d_in[2];
    const int*   mask  = (const int*)d_in[3];
    const float* Wq = (const float*)d_in[4];
    const float* bq = (const float*)d_in[5];
    const float* Wk = (const float*)d_in[6];
    const float* bk = (const float*)d_in[7];
    const float* Wv = (const float*)d_in[8];
    const float* bv = (const float*)d_in[9];
    float* out = (float*)d_out;

    char* ws = (char*)d_ws;
    const size_t MB = 1024 * 1024;
    unsigned short* Qp    = (unsigned short*)(ws);             // 32MB
    unsigned short* Kc    = (unsigned short*)(ws + 32 * MB);   // 32MB
    unsigned short* Vtc   = (unsigned short*)(ws + 64 * MB);   // 32MB
    unsigned short* probs = (unsigned short*)(ws + 96 * MB);   // 64MB
    unsigned short* wq    = (unsigned short*)(ws + 160 * MB);  // 2MB
    unsigned short* wk    = (unsigned short*)(ws + 162 * MB);  // 2MB
    unsigned short* wv    = (unsigned short*)(ws + 164 * MB);  // 2MB
    float* rowsum = (float*)(ws + 166 * MB);                   // 64KB
    int*   idx    = (int*)(ws + 166 * MB + 64 * 1024);         // 64KB
    int*   cnt    = (int*)(ws + 166 * MB + 128 * 1024);        // 32B
    int*   cntp   = (int*)(ws + 166 * MB + 128 * 1024 + 64);   // 32B

    hipMemsetAsync(rowsum, 0, (size_t)BATCH * SEQ * sizeof(float), stream);
    build_idx<<<BATCH, 256, 0, stream>>>(mask, idx, cnt, cntp);

    cast_bf16_all<<<1536, 256, 0, stream>>>(Wq, Wk, Wv, wq, wk, wv);

    proj_gemm_all<<<dim3(8, 16, 12), dim3(256), 0, stream>>>(
        query, key_, value, wq, wk, wv, Qp, Kc, Vtc, bq, bk, bv,
        idx, cnt, cntp);

    scores_gemm<<<dim3(8, 16, 8), dim3(256), 0, stream>>>(
        Qp, Kc, probs, rowsum, cnt, cntp, 0.03125f);

    pv_gemm<<<dim3(8, 8, 8), dim3(256), 0, stream>>>(
        probs, Vtc, out, rowsum, cntp);
}

// Round 5
// 427.301 us; speedup vs baseline: 1.0401x; 1.0196x over previous
//
#include <hip/hip_runtime.h>

// SelfAttention B=8 S=2048 D=1024 fp32 -> fp32, bf16 MFMA internally.
// R9: attack per-K-step drain cost (the surviving theory after R7/R8 nulls):
//     (a) BK=64 (2-panel linear LDS layout keeps gload_lds lane-linear):
//         16 drain-paying steps instead of 32, 2x MFMA per drain.
//     (b) pre-cast gathered K/V to bf16 (cast_kv -> Kg/Vg aliased on the dead
//         probs region): K/V proj become pure m97-style gload_lds GEMMs.
//         Q proj keeps fused fp32->bf16 A-cast (reg-prefetch, BK=64).
// Pipeline:
//   build_idx; castW; cast_kv (gather+compact+zero-pad);
//   proj_gemm_all (one dispatch): Q fused-cast | K pure | V pure (TROUT)
//   scores GEMM (R8 fat-tile): exp(s/32) -> bf16 probs + atomic rowsum
//   pv GEMM (R8 fat-tile), epilogue /rowsum -> fp32 out.
// Workspace: Qp[0,32M) Kc[32,64M) Vtc[64,96M) probs|Kg+Vg[96,160M)
//   weights[160,166M) rowsum/idx/cnt/cntp after.  (Kg/Vg dead before scores
//   writes probs over them; stream-ordered.)

#define BATCH 8
#define SEQ   2048
#define DM    1024

typedef __bf16 bf16x8 __attribute__((ext_vector_type(8)));
typedef float  f32x4  __attribute__((ext_vector_type(4)));
typedef unsigned short ushort8 __attribute__((ext_vector_type(8)));
typedef unsigned short ushort4v __attribute__((ext_vector_type(4)));

__device__ __forceinline__ unsigned short f2b(float f) {
    __bf16 h = (__bf16)f;               // v_cvt_pk_bf16_f32 pairs (RNE)
    return __builtin_bit_cast(unsigned short, h);
}

__device__ __forceinline__ void stage_async(const unsigned short* g,
                                            unsigned short* l) {
    __builtin_amdgcn_global_load_lds(
        (const __attribute__((address_space(1))) void*)g,
        (__attribute__((address_space(3))) void*)l, 16, 0, 0);
}

// fragment load + 4x4 MFMA for one BK=32 panel (128x32 linear LDS)
__device__ __forceinline__ void frag_mfma(const unsigned short* As,
                                          const unsigned short* Bs,
                                          f32x4 acc[4][4], int waveM, int waveN,
                                          int quad, int l16) {
    bf16x8 af[4], bf[4];
#pragma unroll
    for (int i = 0; i < 4; ++i)
        af[i] = *(const bf16x8*)(As + (waveM * 64 + i * 16 + l16) * 32 + quad * 8);
#pragma unroll
    for (int j = 0; j < 4; ++j)
        bf[j] = *(const bf16x8*)(Bs + (waveN * 64 + j * 16 + l16) * 32 + quad * 8);
#pragma unroll
    for (int i = 0; i < 4; ++i)
#pragma unroll
        for (int j = 0; j < 4; ++j)
            acc[i][j] = __builtin_amdgcn_mfma_f32_16x16x32_bf16(
                af[i], bf[j], acc[i][j], 0, 0, 0);
}

// fragment load + 4x8 MFMA for one BK=32 staged tile (scores/pv fat tile)
__device__ __forceinline__ void frag_mfma48(const unsigned short* As,
                                            const unsigned short* Bs,
                                            f32x4 acc[4][8], int waveM,
                                            int waveN, int quad, int l16) {
    bf16x8 af[4], bf[8];
#pragma unroll
    for (int i = 0; i < 4; ++i)
        af[i] = *(const bf16x8*)(As + (waveM * 64 + i * 16 + l16) * 32 + quad * 8);
#pragma unroll
    for (int j = 0; j < 8; ++j)
        bf[j] = *(const bf16x8*)(Bs + (waveN * 128 + j * 16 + l16) * 32 + quad * 8);
#pragma unroll
    for (int i = 0; i < 4; ++i)
#pragma unroll
        for (int j = 0; j < 8; ++j)
            acc[i][j] = __builtin_amdgcn_mfma_f32_16x16x32_bf16(
                af[i], bf[j], acc[i][j], 0, 0, 0);
}

// ---------------- per-batch mask compaction index ----------------
__global__ __launch_bounds__(256) void build_idx(
    const int* __restrict__ mask, int* __restrict__ idx,
    int* __restrict__ cnt, int* __restrict__ cntp) {
    const int b = blockIdx.x;
    const int* m = mask + b * SEQ;
    const int t = threadIdx.x;
    __shared__ int sums[256];
    int loc[8], s = 0;
#pragma unroll
    for (int u = 0; u < 8; ++u) { loc[u] = (m[t * 8 + u] != 0); s += loc[u]; }
    sums[t] = s;
    __syncthreads();
    for (int off = 1; off < 256; off <<= 1) {
        int v = (t >= off) ? sums[t - off] : 0;
        __syncthreads();
        sums[t] += v;
        __syncthreads();
    }
    int base = sums[t] - s;   // exclusive prefix
#pragma unroll
    for (int u = 0; u < 8; ++u)
        if (loc[u]) idx[b * SEQ + base++] = t * 8 + u;
    if (t == 255) {
        cnt[b] = sums[255];
        cntp[b] = (sums[255] + 127) & ~127;
    }
}

// ---------------- cast fp32 -> bf16 (all three weight matrices) ----------------
__global__ void cast_bf16_all(const float* __restrict__ Wq,
                              const float* __restrict__ Wk,
                              const float* __restrict__ Wv,
                              unsigned short* __restrict__ wq,
                              unsigned short* __restrict__ wk,
                              unsigned short* __restrict__ wv) {
    const int p = blockIdx.x >> 9;          // 512 blocks per matrix
    const int lb = blockIdx.x & 511;
    const float* src = (p == 0) ? Wq : (p == 1) ? Wk : Wv;
    unsigned short* dst = (p == 0) ? wq : (p == 1) ? wk : wv;
    int i = lb * blockDim.x + threadIdx.x;  // < 131072
    const f32x4* s4 = (const f32x4*)src;
    f32x4 a = s4[2 * i], b = s4[2 * i + 1];
    ushort8 o;
    o[0] = f2b(a[0]); o[1] = f2b(a[1]); o[2] = f2b(a[2]); o[3] = f2b(a[3]);
    o[4] = f2b(b[0]); o[5] = f2b(b[1]); o[6] = f2b(b[2]); o[7] = f2b(b[3]);
    ((ushort8*)dst)[i] = o;
}

// -------- gather + compact + cast key/value rows to bf16 (zero-pad) --------
// grid 16384 x 256: b>>13 selects key/value; 2 rows per block.
__global__ __launch_bounds__(256) void cast_kv(
    const float* __restrict__ key, const float* __restrict__ value,
    unsigned short* __restrict__ Kg, unsigned short* __restrict__ Vg,
    const int* __restrict__ idx, const int* __restrict__ cnt,
    const int* __restrict__ cntp) {
    const int b = blockIdx.x;
    const int p = b >> 13;
    const int r = b & 8191;
    const int bz = r >> 10;
    const int rowpair = r & 1023;
    const int t = threadIdx.x;
    const int row = rowpair * 2 + (t >> 7);
    if (row >= cntp[bz]) return;
    const int col0 = (t & 127) * 8;
    const float* src = p ? value : key;
    unsigned short* dst = p ? Vg : Kg;
    ushort8 o = {};
    if (row < cnt[bz]) {
        const int srow = idx[bz * SEQ + row];
        const f32x4* s4 =
            (const f32x4*)(src + ((size_t)bz * SEQ + srow) * DM + col0);
        f32x4 a = s4[0], c = s4[1];
        o[0] = f2b(a[0]); o[1] = f2b(a[1]); o[2] = f2b(a[2]); o[3] = f2b(a[3]);
        o[4] = f2b(c[0]); o[5] = f2b(c[1]); o[6] = f2b(c[2]); o[7] = f2b(c[3]);
    }
    *(ushort8*)(dst + ((size_t)bz * SEQ + row) * DM + col0) = o;
}

// ---------------- proj epilogue (bias add, optional transpose out) ----------
template <bool TROUT>
__device__ __forceinline__ void proj_epilogue(
    f32x4 acc[4][4], unsigned short* __restrict__ C,
    const float* __restrict__ bias, int bz, int m0, int n0,
    int waveM, int waveN, int quad, int l16) {
    if (!TROUT) {
        unsigned short* Cb = C + (size_t)bz * SEQ * DM;
#pragma unroll
        for (int i = 0; i < 4; ++i) {
            const int gmb = m0 + waveM * 64 + i * 16 + quad * 4;
#pragma unroll
            for (int j = 0; j < 4; ++j) {
                const int gn = n0 + waveN * 64 + j * 16 + l16;
                const float bv = bias[gn];
#pragma unroll
                for (int r = 0; r < 4; ++r)
                    Cb[(size_t)(gmb + r) * DM + gn] = f2b(acc[i][j][r] + bv);
            }
        }
    } else {
        unsigned short* Cb = C + (size_t)bz * (size_t)DM * SEQ;
#pragma unroll
        for (int i = 0; i < 4; ++i) {
            const int gmb = m0 + waveM * 64 + i * 16 + quad * 4;  // compacted j
#pragma unroll
            for (int j = 0; j < 4; ++j) {
                const int gn = n0 + waveN * 64 + j * 16 + l16;
                const float bv = bias[gn];
                ushort4v o;
#pragma unroll
                for (int r = 0; r < 4; ++r) o[r] = f2b(acc[i][j][r] + bv);
                *(ushort4v*)(Cb + (size_t)gn * SEQ + gmb) = o;
            }
        }
    }
}

// ---- pure bf16 projection body (K/V): A from pre-cast compacted Xg ----
// BK=64 via two 128x32 linear panels; 2-barrier single-buffer loop.
template <bool TROUT>
__device__ __forceinline__ void proj_pure_body(
    const unsigned short* __restrict__ Xg, const unsigned short* __restrict__ W,
    unsigned short* __restrict__ C, const float* __restrict__ bias,
    const int* __restrict__ cntp, int bz, int i2,
    unsigned short (*As)[128 * 32], unsigned short (*Bs)[128 * 32]) {
    const int n0 = (i2 & 7) * 128;
    const int m0 = (i2 >> 3) * 128;
    if (m0 >= cntp[bz]) return;

    const int tid = threadIdx.x;
    const int wave = tid >> 6, lane = tid & 63;
    const int waveM = wave >> 1, waveN = wave & 1;
    const int quad = lane >> 4, l16 = lane & 15;

    f32x4 acc[4][4] = {};

    const int sr = lane >> 2, sc = (lane & 3) * 8;
    const unsigned short* gA =
        Xg + (size_t)bz * SEQ * DM + (size_t)(m0 + wave * 32 + sr) * DM + sc;
    const unsigned short* gB = W + (size_t)(n0 + wave * 32 + sr) * DM + sc;
    const int loff = (wave * 32 + sr) * 32 + sc;

    for (int kt = 0; kt < DM; kt += 64) {
#pragma unroll
        for (int ph = 0; ph < 2; ++ph) {
            const int ko = kt + ph * 32;
            stage_async(gA + ko, As[ph] + loff);
            stage_async(gA + ko + 16 * DM, As[ph] + loff + 16 * 32);
            stage_async(gB + ko, Bs[ph] + loff);
            stage_async(gB + ko + 16 * DM, Bs[ph] + loff + 16 * 32);
        }
        __syncthreads();
        frag_mfma(As[0], Bs[0], acc, waveM, waveN, quad, l16);
        frag_mfma(As[1], Bs[1], acc, waveM, waveN, quad, l16);
        __syncthreads();
    }
    proj_epilogue<TROUT>(acc, C, bias, bz, m0, n0, waveM, waveN, quad, l16);
}

// ---- Q projection body: fused fp32->bf16 A-cast, reg-prefetched, BK=64 ----
__device__ __forceinline__ void proj_q_body(
    const float* __restrict__ X, const unsigned short* __restrict__ W,
    unsigned short* __restrict__ C, const float* __restrict__ bias,
    int bz, int i2,
    unsigned short (*As)[128 * 32], unsigned short (*Bs)[128 * 32]) {
    const int n0 = (i2 & 7) * 128;
    const int m0 = (i2 >> 3) * 128;

    const int tid = threadIdx.x;
    const int wave = tid >> 6, lane = tid & 63;
    const int waveM = wave >> 1, waveN = wave & 1;
    const int quad = lane >> 4, l16 = lane & 15;

    f32x4 acc[4][4] = {};

    // A: thread -> row tid>>1, 16-col slot (tid&1)*16 within each 32-col panel
    const int arow = tid >> 1;
    const int col0 = (tid & 1) * 16;
    const float* rp = X + ((size_t)bz * SEQ + m0 + arow) * DM + col0;
    const int lAoff = arow * 32 + col0;

    const int sr = lane >> 2, sc = (lane & 3) * 8;
    const unsigned short* gB = W + (size_t)(n0 + wave * 32 + sr) * DM + sc;
    const int lBoff = (wave * 32 + sr) * 32 + sc;

    // prefetch A tile 0: panel0 cols [0,16), panel1 cols [32,48) rel. to col0
    f32x4 a0, a1, a2, a3, a4, a5, a6, a7;
    {
        const f32x4* p0 = (const f32x4*)(rp);
        const f32x4* p1 = (const f32x4*)(rp + 32);
        a0 = p0[0]; a1 = p0[1]; a2 = p0[2]; a3 = p0[3];
        a4 = p1[0]; a5 = p1[1]; a6 = p1[2]; a7 = p1[3];
    }

    for (int kt = 0; kt < DM; kt += 64) {
#pragma unroll
        for (int ph = 0; ph < 2; ++ph) {
            const int ko = kt + ph * 32;
            stage_async(gB + ko, Bs[ph] + lBoff);
            stage_async(gB + ko + 16 * DM, Bs[ph] + lBoff + 16 * 32);
        }
        // cast current A tile (regs prefetched)
        ushort8 o0, o1, o2, o3;
        o0[0] = f2b(a0[0]); o0[1] = f2b(a0[1]); o0[2] = f2b(a0[2]); o0[3] = f2b(a0[3]);
        o0[4] = f2b(a1[0]); o0[5] = f2b(a1[1]); o0[6] = f2b(a1[2]); o0[7] = f2b(a1[3]);
        o1[0] = f2b(a2[0]); o1[1] = f2b(a2[1]); o1[2] = f2b(a2[2]); o1[3] = f2b(a2[3]);
        o1[4] = f2b(a3[0]); o1[5] = f2b(a3[1]); o1[6] = f2b(a3[2]); o1[7] = f2b(a3[3]);
        o2[0] = f2b(a4[0]); o2[1] = f2b(a4[1]); o2[2] = f2b(a4[2]); o2[3] = f2b(a4[3]);
        o2[4] = f2b(a5[0]); o2[5] = f2b(a5[1]); o2[6] = f2b(a5[2]); o2[7] = f2b(a5[3]);
        o3[0] = f2b(a6[0]); o3[1] = f2b(a6[1]); o3[2] = f2b(a6[2]); o3[3] = f2b(a6[3]);
        o3[4] = f2b(a7[0]); o3[5] = f2b(a7[1]); o3[6] = f2b(a7[2]); o3[7] = f2b(a7[3]);
        *(ushort8*)(As[0] + lAoff) = o0;
        *(ushort8*)(As[0] + lAoff + 8) = o1;
        *(ushort8*)(As[1] + lAoff) = o2;
        *(ushort8*)(As[1] + lAoff + 8) = o3;
        // prefetch next A tile
        if (kt + 64 < DM) {
            const f32x4* p0 = (const f32x4*)(rp + kt + 64);
            const f32x4* p1 = (const f32x4*)(rp + kt + 96);
            a0 = p0[0]; a1 = p0[1]; a2 = p0[2]; a3 = p0[3];
            a4 = p1[0]; a5 = p1[1]; a6 = p1[2]; a7 = p1[3];
        }
        __syncthreads();
        frag_mfma(As[0], Bs[0], acc, waveM, waveN, quad, l16);
        frag_mfma(As[1], Bs[1], acc, waveM, waveN, quad, l16);
        __syncthreads();
    }
    proj_epilogue<false>(acc, C, bias, bz, m0, n0, waveM, waveN, quad, l16);
}

// Merged Q/K/V projection dispatch.  grid (8,16,24): l in [0,3072);
// p = l>>10 selects projection; batch = l&7; i2 = (l&1023)>>3.
__global__ __launch_bounds__(256) void proj_gemm_all(
    const float* __restrict__ q, const unsigned short* __restrict__ Kg,
    const unsigned short* __restrict__ Vg,
    const unsigned short* __restrict__ wq, const unsigned short* __restrict__ wk,
    const unsigned short* __restrict__ wv,
    unsigned short* __restrict__ Qp, unsigned short* __restrict__ Kc,
    unsigned short* __restrict__ Vt, const float* __restrict__ bq,
    const float* __restrict__ bk, const float* __restrict__ bv,
    const int* __restrict__ cntp) {
    const int l = blockIdx.x + 8 * (blockIdx.y + 16 * blockIdx.z);
    const int p = l >> 10;
    const int bz = l & 7;
    const int i2 = (l & 1023) >> 3;   // 0..127

    __shared__ __align__(16) unsigned short As[2][128 * 32];
    __shared__ __align__(16) unsigned short Bs[2][128 * 32];

    if (p == 0)
        proj_q_body(q, wq, Qp, bq, bz, i2, As, Bs);
    else if (p == 1)
        proj_pure_body<false>(Kg, wk, Kc, bk, cntp, bz, i2, As, Bs);
    else
        proj_pure_body<true>(Vg, wv, Vt, bv, cntp, bz, i2, As, Bs);
}

// ---------------- scores GEMM: probs = exp(Q.Kc^T/32), + rowsum ----------------
// 128x256 tiles: grid (8,16,8): l in [0,1024); bz=l&7; i2=l>>3: nt=i2&7, mt=i2>>3.
__global__ __launch_bounds__(256, 2) void scores_gemm(
    const unsigned short* __restrict__ Qp, const unsigned short* __restrict__ Kc,
    unsigned short* __restrict__ P, float* __restrict__ rowsum,
    const int* __restrict__ cnt, const int* __restrict__ cntp, float scale) {
    const int l = blockIdx.x + 8 * (blockIdx.y + 16 * blockIdx.z);
    const int bz = l & 7;
    const int i2 = l >> 3;            // 0..127
    const int n0 = (i2 & 7) * 256;
    const int m0 = (i2 >> 3) * 128;
    if (n0 >= cntp[bz]) return;

    const int tid = threadIdx.x;
    const int wave = tid >> 6, lane = tid & 63;
    const int waveM = wave >> 1, waveN = wave & 1;
    const int quad = lane >> 4, l16 = lane & 15;

    __shared__ __align__(16) unsigned short As[2][128 * 32];
    __shared__ __align__(16) unsigned short Bs[2][256 * 32];
    f32x4 acc[4][8] = {};

    const unsigned short* Ag = Qp + (size_t)bz * SEQ * DM;
    const unsigned short* Bg = Kc + (size_t)bz * SEQ * DM;
    const int sr = lane >> 2, sc = (lane & 3) * 8;
    const unsigned short* gA = Ag + (size_t)(m0 + wave * 32 + sr) * DM + sc;
    const unsigned short* gB = Bg + (size_t)(n0 + wave * 16 + sr) * DM + sc;
    const int lAoff = (wave * 32 + sr) * 32 + sc;
    const int lBoff = (wave * 16 + sr) * 32 + sc;

    stage_async(gA, As[0] + lAoff);
    stage_async(gA + 16 * DM, As[0] + lAoff + 16 * 32);
#pragma unroll
    for (int c = 0; c < 4; ++c)
        stage_async(gB + (size_t)c * 64 * DM, Bs[0] + lBoff + c * 64 * 32);
    __syncthreads();

    int cur = 0;
    for (int kt = 0; kt < DM; kt += 32) {
        const int nx = kt + 32;
        if (nx < DM) {
            unsigned short* Asn = cur ? As[0] : As[1];
            unsigned short* Bsn = cur ? Bs[0] : Bs[1];
            stage_async(gA + nx, Asn + lAoff);
            stage_async(gA + nx + 16 * DM, Asn + lAoff + 16 * 32);
#pragma unroll
            for (int c = 0; c < 4; ++c)
                stage_async(gB + (size_t)c * 64 * DM + nx,
                            Bsn + lBoff + c * 64 * 32);
        }
        frag_mfma48(cur ? As[1] : As[0], cur ? Bs[1] : Bs[0], acc,
                    waveM, waveN, quad, l16);
        __syncthreads();
        cur ^= 1;
    }

    unsigned short* Cb = P + (size_t)bz * SEQ * SEQ;
    const int cn = cnt[bz];
#pragma unroll
    for (int i = 0; i < 4; ++i) {
        const int gmb = m0 + waveM * 64 + i * 16 + quad * 4;
        float rpart[4] = {0.f, 0.f, 0.f, 0.f};
#pragma unroll
        for (int j = 0; j < 8; ++j) {
            const int gn = n0 + waveN * 128 + j * 16 + l16;
            const float mv = (gn < cn) ? 1.0f : 0.0f;
#pragma unroll
            for (int r = 0; r < 4; ++r) {
                const float p = mv * __expf(acc[i][j][r] * scale);
                rpart[r] += p;
                Cb[(size_t)(gmb + r) * SEQ + gn] = f2b(p);
            }
        }
#pragma unroll
        for (int r = 0; r < 4; ++r) {
            float s = rpart[r];
            s += __shfl_xor(s, 1, 64);
            s += __shfl_xor(s, 2, 64);
            s += __shfl_xor(s, 4, 64);
            s += __shfl_xor(s, 8, 64);
            if (l16 == 0)
                atomicAdd(&rowsum[bz * SEQ + gmb + r], s);
        }
    }
}

// ---------------- PV GEMM: out = (P.Vtc^T) / rowsum ----------------
// 128x256 tiles: grid (8,8,8): l in [0,512); bz=l&7; i2=l>>3: nt=i2&3, mt=i2>>2.
__global__ __launch_bounds__(256, 2) void pv_gemm(
    const unsigned short* __restrict__ P, const unsigned short* __restrict__ Vt,
    float* __restrict__ O, const float* __restrict__ rowsum,
    const int* __restrict__ cntp) {
    const int l = blockIdx.x + 8 * (blockIdx.y + 8 * blockIdx.z);
    const int bz = l & 7;
    const int i2 = l >> 3;            // 0..63
    const int n0 = (i2 & 3) * 256;
    const int m0 = (i2 >> 2) * 128;
    const int kend = cntp[bz];

    const int tid = threadIdx.x;
    const int wave = tid >> 6, lane = tid & 63;
    const int waveM = wave >> 1, waveN = wave & 1;
    const int quad = lane >> 4, l16 = lane & 15;

    __shared__ __align__(16) unsigned short As[2][128 * 32];
    __shared__ __align__(16) unsigned short Bs[2][256 * 32];
    f32x4 acc[4][8] = {};

    const unsigned short* Ag = P + (size_t)bz * SEQ * SEQ;
    const unsigned short* Bg = Vt + (size_t)bz * (size_t)DM * SEQ;
    const int sr = lane >> 2, sc = (lane & 3) * 8;
    const unsigned short* gA = Ag + (size_t)(m0 + wave * 32 + sr) * SEQ + sc;
    const unsigned short* gB = Bg + (size_t)(n0 + wave * 16 + sr) * SEQ + sc;
    const int lAoff = (wave * 32 + sr) * 32 + sc;
    const int lBoff = (wave * 16 + sr) * 32 + sc;

    stage_async(gA, As[0] + lAoff);
    stage_async(gA + 16 * SEQ, As[0] + lAoff + 16 * 32);
#pragma unroll
    for (int c = 0; c < 4; ++c)
        stage_async(gB + (size_t)c * 64 * SEQ, Bs[0] + lBoff + c * 64 * 32);
    __syncthreads();

    int cur = 0;
    for (int kt = 0; kt < kend; kt += 32) {
        const int nx = kt + 32;
        if (nx < kend) {
            unsigned short* Asn = cur ? As[0] : As[1];
            unsigned short* Bsn = cur ? Bs[0] : Bs[1];
            stage_async(gA + nx, Asn + lAoff);
            stage_async(gA + nx + 16 * SEQ, Asn + lAoff + 16 * 32);
#pragma unroll
            for (int c = 0; c < 4; ++c)
                stage_async(gB + (size_t)c * 64 * SEQ + nx,
                            Bsn + lBoff + c * 64 * 32);
        }
        frag_mfma48(cur ? As[1] : As[0], cur ? Bs[1] : Bs[0], acc,
                    waveM, waveN, quad, l16);
        __syncthreads();
        cur ^= 1;
    }

    float* Cb = O + (size_t)bz * SEQ * DM;
#pragma unroll
    for (int i = 0; i < 4; ++i) {
        const int gmb = m0 + waveM * 64 + i * 16 + quad * 4;
        float inv[4];
#pragma unroll
        for (int r = 0; r < 4; ++r)
            inv[r] = 1.0f / rowsum[bz * SEQ + gmb + r];
#pragma unroll
        for (int j = 0; j < 8; ++j) {
            const int gn = n0 + waveN * 128 + j * 16 + l16;
#pragma unroll
            for (int r = 0; r < 4; ++r)
                Cb[(size_t)(gmb + r) * DM + gn] = acc[i][j][r] * inv[r];
        }
    }
}

extern "C" void kernel_launch(void* const* d_in, const int* in_sizes, int n_in,
                              void* d_out, int out_size, void* d_ws, size_t ws_size,
                              hipStream_t stream) {
    const float* query = (const float*)d_in[0];
    const float* key_  = (const float*)d_in[1];
    const float* value = (const float*)d_in[2];
    const int*   mask  = (const int*)d_in[3];
    const float* Wq = (const float*)d_in[4];
    const float* bq = (const float*)d_in[5];
    const float* Wk = (const float*)d_in[6];
    const float* bk = (const float*)d_in[7];
    const float* Wv = (const float*)d_in[8];
    const float* bv = (const float*)d_in[9];
    float* out = (float*)d_out;

    char* ws = (char*)d_ws;
    const size_t MB = 1024 * 1024;
    unsigned short* Qp    = (unsigned short*)(ws);             // 32MB
    unsigned short* Kc    = (unsigned short*)(ws + 32 * MB);   // 32MB
    unsigned short* Vtc   = (unsigned short*)(ws + 64 * MB);   // 32MB
    unsigned short* probs = (unsigned short*)(ws + 96 * MB);   // 64MB
    unsigned short* Kg    = probs;                             // alias (dead
    unsigned short* Vg    = (unsigned short*)(ws + 128 * MB);  //  before scores)
    unsigned short* wq    = (unsigned short*)(ws + 160 * MB);  // 2MB
    unsigned short* wk    = (unsigned short*)(ws + 162 * MB);  // 2MB
    unsigned short* wv    = (unsigned short*)(ws + 164 * MB);  // 2MB
    float* rowsum = (float*)(ws + 166 * MB);                   // 64KB
    int*   idx    = (int*)(ws + 166 * MB + 64 * 1024);         // 64KB
    int*   cnt    = (int*)(ws + 166 * MB + 128 * 1024);        // 32B
    int*   cntp   = (int*)(ws + 166 * MB + 128 * 1024 + 64);   // 32B

    hipMemsetAsync(rowsum, 0, (size_t)BATCH * SEQ * sizeof(float), stream);
    build_idx<<<BATCH, 256, 0, stream>>>(mask, idx, cnt, cntp);

    cast_bf16_all<<<1536, 256, 0, stream>>>(Wq, Wk, Wv, wq, wk, wv);
    cast_kv<<<16384, 256, 0, stream>>>(key_, value, Kg, Vg, idx, cnt, cntp);

    proj_gemm_all<<<dim3(8, 16, 24), dim3(256), 0, stream>>>(
        query, Kg, Vg, wq, wk, wv, Qp, Kc, Vtc, bq, bk, bv, cntp);

    scores_gemm<<<dim3(8, 16, 8), dim3(256), 0, stream>>>(
        Qp, Kc, probs, rowsum, cnt, cntp, 0.03125f);

    pv_gemm<<<dim3(8, 8, 8), dim3(256), 0, stream>>>(
        probs, Vtc, out, rowsum, cntp);
}